// Round 5
// baseline (5829.845 us; speedup 1.0000x reference)
//
#include <hip/hip_runtime.h>
#include <cstdint>
#include <cstddef>

// ---------------- problem constants ----------------
#define BATCH   128
#define SEQ     512
#define TOKENS  (BATCH * SEQ)   // 65536
#define EMB_D   300
#define KA0     320             // padded E
#define HID     256
#define G4H     1024            // 4*H
#define KA1     512             // 2*H
#define NTAGS   9
#define CHUNK   128             // seq chunk per round
#define CTOK    (BATCH * CHUNK) // 16384 rows per dir per round

typedef _Float16 f16;
typedef _Float16 f16x2 __attribute__((ext_vector_type(2)));
typedef _Float16 f16x8 __attribute__((ext_vector_type(8)));
typedef float    f32x4 __attribute__((ext_vector_type(4)));

// ---------------- workspace layout (bytes), total ~202 MB ----------------
static constexpr size_t XW_BYTES   = (size_t)2 * CTOK * G4H * 2;    // 67,108,864
static constexpr size_t H_BYTES    = (size_t)TOKENS * KA1 * 2;      // 67,108,864
static constexpr size_t POOL_BYTES = H_BYTES;                       // e16 (40MB) then h1 (64MB)
static constexpr size_t EM_BYTES   = (size_t)TOKENS * 16 * 4;       // 4,194,304
static constexpr size_t WHH_BYTES  = (size_t)4 * G4H * HID * 2;     // 2,097,152
static constexpr size_t WIH0_BYTES = (size_t)2 * G4H * KA0 * 2;     // 1,310,720
static constexpr size_t WIH1_BYTES = (size_t)2 * G4H * KA1 * 2;     // 2,097,152
static constexpr size_t FCW_BYTES  = (size_t)128 * KA1 * 2;         // 131,072
static constexpr size_t FCB_BYTES  = 512;
static constexpr size_t STH_BYTES  = (size_t)2 * BATCH * HID * 2;   // 131,072
static constexpr size_t STC_BYTES  = (size_t)2 * BATCH * HID * 4;   // 262,144
static constexpr size_t NLL_BYTES  = 512;

static constexpr size_t OFF_XW   = 0;
static constexpr size_t OFF_H0   = OFF_XW   + XW_BYTES;
static constexpr size_t OFF_POOL = OFF_H0   + H_BYTES;    // e16 and h1 alias here
static constexpr size_t OFF_EM   = OFF_POOL + POOL_BYTES;
static constexpr size_t OFF_WHH  = OFF_EM   + EM_BYTES;
static constexpr size_t OFF_WIH0 = OFF_WHH  + WHH_BYTES;
static constexpr size_t OFF_WIH1 = OFF_WIH0 + WIH0_BYTES;
static constexpr size_t OFF_FCW  = OFF_WIH1 + WIH1_BYTES;
static constexpr size_t OFF_FCB  = OFF_FCW  + FCW_BYTES;
static constexpr size_t OFF_STH  = OFF_FCB  + FCB_BYTES;
static constexpr size_t OFF_STC  = OFF_STH  + STH_BYTES;
static constexpr size_t OFF_NLL  = OFF_STC  + STC_BYTES;

// ---------------- helpers ----------------
__device__ inline float fdot2(uint32_t a, uint32_t b, float c) {
#if __has_builtin(__builtin_amdgcn_fdot2)
  return __builtin_amdgcn_fdot2(__builtin_bit_cast(f16x2, a),
                                __builtin_bit_cast(f16x2, b), c, false);
#else
  f16x2 ha = __builtin_bit_cast(f16x2, a), hb = __builtin_bit_cast(f16x2, b);
  return c + (float)ha.x * (float)hb.x + (float)ha.y * (float)hb.y;
#endif
}

// LDS chunk swizzle to spread b128 frag reads across banks (GEMM)
__device__ inline int swz(int r, int q) { return q ^ ((r & 3) ^ ((r >> 2) & 3)); }

// ---------------- prep: fp32 -> fp16 weight packing ----------------
__global__ void prep_kernel(
    const float* whh_l0f, const float* whh_l0b, const float* whh_l1f, const float* whh_l1b,
    const float* wih_l0f, const float* wih_l0b,
    const float* wih_l1f, const float* wih_l1b,
    const float* fc_w, const float* fc_b,
    f16* whh16, f16* wih0_16, f16* wih1_16, f16* fcw16, float* fcb32)
{
  int id = blockIdx.x * 256 + threadIdx.x;
  if (id < 1048576) {               // whh: [4][1024][256]
    int which = id >> 18; int off = id & 262143;
    const float* s = which == 0 ? whh_l0f : which == 1 ? whh_l0b
                   : which == 2 ? whh_l1f : whh_l1b;
    whh16[id] = (f16)s[off];
    return;
  }
  id -= 1048576;
  if (id < 655360) {                // wih l0 padded: [2][1024][320]
    int dir = id / 327680; int rem = id - dir * 327680;
    int r = rem / KA0; int k = rem - r * KA0;
    const float* s = dir ? wih_l0b : wih_l0f;
    wih0_16[id] = (f16)(k < EMB_D ? s[r * EMB_D + k] : 0.f);
    return;
  }
  id -= 655360;
  if (id < 1048576) {               // wih l1: [2][1024][512]
    const float* s = (id < 524288) ? wih_l1f : wih_l1b;
    wih1_16[id] = (f16)s[id & 524287];
    return;
  }
  id -= 1048576;
  if (id < 65536) {                 // fcw: [128][512], rows >= 9 zero
    int r = id >> 9;
    fcw16[id] = (f16)(r < NTAGS ? fc_w[id] : 0.f);
    return;
  }
  id -= 65536;
  if (id < 128) fcb32[id] = id < NTAGS ? fc_b[id] : 0.f;
}

// ---------------- embedding gather -> f16 padded ----------------
__global__ void embed_kernel(const int* __restrict__ x, const float* __restrict__ emb,
                             f16* __restrict__ e16)
{
  int id = blockIdx.x * 256 + threadIdx.x;   // over TOKENS*KA0
  if (id >= TOKENS * KA0) return;
  int row = id / KA0, k = id - row * KA0;
  float v = 0.f;
  if (k < EMB_D) v = emb[(size_t)x[row] * EMB_D + k];
  e16[id] = (f16)v;
}

// ---------------- MFMA f16 GEMM: C[M][N] = A[rowmap(M)][K] * B[N][K]^T + bias ----
// 128x128 tile, BK=32, 256 threads (4 waves, 2x2 of 64x64).
__global__ __launch_bounds__(256, 3) void gemm_kernel(
    const f16* __restrict__ A, int lda, int aGrpStride,
    const f16* __restrict__ B0, const f16* __restrict__ B1, int ldb,
    const float* __restrict__ bias0, const float* __restrict__ bias1,
    f16* outH, float* outF, int ldc, size_t outZStride,
    int kChunks, int nLimit, int cbF, int cbB)
{
  __shared__ __align__(16) f16 As[128 * 32];
  __shared__ __align__(16) f16 Bs[128 * 32];
  const int z = blockIdx.z;
  const f16* B = z ? B1 : B0;
  const float* bias = z ? bias1 : bias0;
  const int cb = z ? cbB : cbF;
  const int m0 = blockIdx.x * 128, n0 = blockIdx.y * 128;
  const int aBase = (m0 >> 7) * aGrpStride + cb;
  const int tid = threadIdx.x;
  const int w = tid >> 6, lane = tid & 63;
  const int mw = (w & 1) * 64, nw = (w >> 1) * 64;
  const int fr = lane & 15, fq = lane >> 4;

  f32x4 acc[4][4];
#pragma unroll
  for (int i = 0; i < 4; ++i)
#pragma unroll
    for (int j = 0; j < 4; ++j) acc[i][j] = (f32x4)(0.f);

  const int c0 = tid, c1 = tid + 256;
  const int r0 = c0 >> 2, q0 = c0 & 3, r1c = c1 >> 2, q1 = c1 & 3;

  for (int kc = 0; kc < kChunks; ++kc) {
    const int k0 = kc * 32;
    uint4 a0v = *(const uint4*)(A + (size_t)(aBase + r0)  * lda + k0 + q0 * 8);
    uint4 a1v = *(const uint4*)(A + (size_t)(aBase + r1c) * lda + k0 + q1 * 8);
    uint4 b0v = *(const uint4*)(B + (size_t)(n0 + r0)  * ldb + k0 + q0 * 8);
    uint4 b1v = *(const uint4*)(B + (size_t)(n0 + r1c) * ldb + k0 + q1 * 8);
    __syncthreads();
    *(uint4*)(As + r0  * 32 + swz(r0,  q0) * 8) = a0v;
    *(uint4*)(As + r1c * 32 + swz(r1c, q1) * 8) = a1v;
    *(uint4*)(Bs + r0  * 32 + swz(r0,  q0) * 8) = b0v;
    *(uint4*)(Bs + r1c * 32 + swz(r1c, q1) * 8) = b1v;
    __syncthreads();
    f16x8 af[4], bf[4];
#pragma unroll
    for (int i = 0; i < 4; ++i) {
      int rr = mw + i * 16 + fr;
      af[i] = *(const f16x8*)(As + rr * 32 + swz(rr, fq) * 8);
    }
#pragma unroll
    for (int j = 0; j < 4; ++j) {
      int rr = nw + j * 16 + fr;
      bf[j] = *(const f16x8*)(Bs + rr * 32 + swz(rr, fq) * 8);
    }
#pragma unroll
    for (int i = 0; i < 4; ++i)
#pragma unroll
      for (int j = 0; j < 4; ++j)
        acc[i][j] = __builtin_amdgcn_mfma_f32_16x16x32_f16(af[i], bf[j], acc[i][j], 0, 0, 0);
  }
  // epilogue: C row = (lane>>4)*4 + r, col = lane&15
  f16* oH = outH ? outH + (size_t)z * outZStride : nullptr;
  float* oF = outF;
#pragma unroll
  for (int j = 0; j < 4; ++j) {
    int n = n0 + nw + j * 16 + fr;
    if (n >= nLimit) continue;
    float bs = bias ? bias[n] : 0.f;
#pragma unroll
    for (int i = 0; i < 4; ++i) {
#pragma unroll
      for (int r = 0; r < 4; ++r) {
        int m = m0 + mw + i * 16 + fq * 4 + r;
        float v = acc[i][j][r] + bs;
        if (oH) oH[(size_t)m * ldc + n] = (f16)v;
        else    oF[(size_t)m * ldc + n] = v;
      }
    }
  }
}

// ---------------- persistent LSTM recurrence, 128-step chunk ----------------
// grid 256 = (dir, batch); 1024 threads. Thread (n = tid&255, ks = tid>>8)
// computes partial dots of gates {i,f,g,o} for h-col n over K-seg
// [ks*64, ks*64+64). Weights (4 gates x 64 f16 = 128 dwords) live in the
// unified VGPR/AGPR file. h broadcast: 8 uint4 LDS reads/thread/step, reused
// across all 4 gates. xW terms are owned by the ks==0 (activation) threads
// ONLY and added once during the reduction — adding them in the dot phase
// would count them 4x (the r4 bug).
__global__ __launch_bounds__(1024) void rec_kernel(
    const f16* __restrict__ xw,            // [2][128][CHUNK][1024] f16
    const uint32_t* __restrict__ whh_f, const uint32_t* __restrict__ whh_b,
    f16* __restrict__ hout,
    f16* __restrict__ stateH, float* __restrict__ stateC, int r)
{
  __shared__ __align__(16) uint4 hb[2][32];       // h double buffer (256 f16 each)
  __shared__ __align__(16) f32x4 part[1024];      // 16 KB partials [ks*256+n]
  const int tau = threadIdx.x;
  const int n   = tau & 255;
  const int ks  = tau >> 8;
  const int bid = blockIdx.x;
  const int dir = bid >> 7;
  const int b   = bid & 127;
  const int chunk = dir ? (3 - r) : r;
  const int tBase = chunk * CHUNK;
  const uint32_t* whh = dir ? whh_b : whh_f;
  const f16* xwp = xw + (size_t)(dir * 128 + b) * CHUNK * 1024;

  // weight preload: gate rows g*256+n, dword cols [ks*32, ks*32+32)
  uint4 wv[4][8];
#pragma unroll
  for (int g = 0; g < 4; ++g) {
    const uint4* p = (const uint4*)(whh) + (size_t)(g * 256 + n) * 32 + ks * 8;
#pragma unroll
    for (int i = 0; i < 8; ++i) wv[g][i] = p[i];
  }
  float cst = 0.f;
  if (tau < 256) {
    f16 hi = (f16)0.f;
    if (r) { hi = stateH[(dir * 128 + b) * 256 + tau]; cst = stateC[(dir * 128 + b) * 256 + tau]; }
    ((f16*)hb[0])[tau] = hi;
  }
  __syncthreads();

  // xW values: only the activation threads (ks==0) carry them
  f16 xc0 = (f16)0.f, xc1 = (f16)0.f, xc2 = (f16)0.f, xc3 = (f16)0.f;
  if (ks == 0) {
    int lr0 = dir ? (CHUNK - 1) : 0;
    const f16* q = xwp + lr0 * 1024;
    xc0 = q[n]; xc1 = q[256 + n]; xc2 = q[512 + n]; xc3 = q[768 + n];
  }

  for (int s = 0; s < CHUNK; ++s) {
    const int lrow = dir ? (CHUNK - 1 - s) : s;
    const size_t token = (size_t)b * 512 + tBase + lrow;
    const int cur = s & 1, nxt = cur ^ 1;
    // prefetch next step's xW (ks==0 only; wave-uniform branch)
    f16 xn0 = (f16)0.f, xn1 = (f16)0.f, xn2 = (f16)0.f, xn3 = (f16)0.f;
    if (ks == 0 && s < CHUNK - 1) {
      int lrn = dir ? (CHUNK - 2 - s) : (s + 1);
      const f16* q = xwp + lrn * 1024;
      xn0 = q[n]; xn1 = q[256 + n]; xn2 = q[512 + n]; xn3 = q[768 + n];
    }
    // h segment: 8 broadcast b128 reads, shared by all 4 gates
    uint4 hv[8];
    {
      const uint4* hp = hb[cur] + ks * 8;
#pragma unroll
      for (int i = 0; i < 8; ++i) hv[i] = hp[i];
    }
    float a0 = 0.f, a1 = 0.f, a2 = 0.f, a3 = 0.f;
#pragma unroll
    for (int i = 0; i < 8; ++i) {
      uint4 h4 = hv[i];
      a0 = fdot2(wv[0][i].x, h4.x, a0); a0 = fdot2(wv[0][i].y, h4.y, a0);
      a0 = fdot2(wv[0][i].z, h4.z, a0); a0 = fdot2(wv[0][i].w, h4.w, a0);
      a1 = fdot2(wv[1][i].x, h4.x, a1); a1 = fdot2(wv[1][i].y, h4.y, a1);
      a1 = fdot2(wv[1][i].z, h4.z, a1); a1 = fdot2(wv[1][i].w, h4.w, a1);
      a2 = fdot2(wv[2][i].x, h4.x, a2); a2 = fdot2(wv[2][i].y, h4.y, a2);
      a2 = fdot2(wv[2][i].z, h4.z, a2); a2 = fdot2(wv[2][i].w, h4.w, a2);
      a3 = fdot2(wv[3][i].x, h4.x, a3); a3 = fdot2(wv[3][i].y, h4.y, a3);
      a3 = fdot2(wv[3][i].w, h4.w, a3); a3 = fdot2(wv[3][i].z, h4.z, a3);
    }
    f32x4 pk; pk[0] = a0; pk[1] = a1; pk[2] = a2; pk[3] = a3;
    part[tau] = pk;                       // lane-contiguous, conflict-free
    __syncthreads();
    if (tau < 256) {
      f32x4 p0 = part[n], p1 = part[256 + n], p2 = part[512 + n], p3 = part[768 + n];
      float gi = p0[0] + p1[0] + p2[0] + p3[0] + (float)xc0;
      float gf = p0[1] + p1[1] + p2[1] + p3[1] + (float)xc1;
      float gg = p0[2] + p1[2] + p2[2] + p3[2] + (float)xc2;
      float go = p0[3] + p1[3] + p2[3] + p3[3] + (float)xc3;
      float si = 1.f / (1.f + __expf(-gi));
      float sf = 1.f / (1.f + __expf(-gf));
      float so = 1.f / (1.f + __expf(-go));
      float e2 = __expf(2.f * gg); float tg = 1.f - 2.f / (e2 + 1.f);
      cst = sf * cst + si * tg;
      e2 = __expf(2.f * cst); float tc = 1.f - 2.f / (e2 + 1.f);
      float h = so * tc;
      f16 hh = (f16)h;
      ((f16*)hb[nxt])[tau] = hh;
      hout[token * 512 + dir * 256 + tau] = hh;
    }
    __syncthreads();
    xc0 = xn0; xc1 = xn1; xc2 = xn2; xc3 = xn3;
  }
  // CHUNK even -> final h in hb[0]
  if (tau < 256) {
    stateH[(dir * 128 + b) * 256 + tau] = ((f16*)hb[0])[tau];
    stateC[(dir * 128 + b) * 256 + tau] = cst;
  }
}

// ---------------- CRF: one wave per batch element ----------------
__global__ void crf_kernel(const float* __restrict__ em, const int* __restrict__ tags,
                           const float* __restrict__ start, const float* __restrict__ endv,
                           const float* __restrict__ trans, float* __restrict__ nll)
{
  const int b = blockIdx.x;
  const int lane = threadIdx.x;  // 64
  const float* emb_ = em + (size_t)b * SEQ * 16;
  const int* tg = tags + b * SEQ;

  // numerator, parallel over t
  float numacc = 0.f;
  for (int t = lane; t < SEQ; t += 64) {
    int ct = tg[t];
    numacc += emb_[t * 16 + ct];
    if (t > 0) numacc += trans[tg[t - 1] * NTAGS + ct];
  }
#pragma unroll
  for (int s = 32; s; s >>= 1) numacc += __shfl_xor(numacc, s);

  // forward algorithm: lanes 0..8 hold alpha_j
  int jj = lane < NTAGS ? lane : 0;
  float tr[NTAGS];
#pragma unroll
  for (int i = 0; i < NTAGS; ++i) tr[i] = trans[i * NTAGS + jj];
  float alpha = (lane < NTAGS) ? (start[lane] + emb_[lane]) : -1e30f;
  for (int t = 1; t < SEQ; ++t) {
    float va[NTAGS];
#pragma unroll
    for (int i = 0; i < NTAGS; ++i) va[i] = __shfl(alpha, i) + tr[i];
    float mx = va[0];
#pragma unroll
    for (int i = 1; i < NTAGS; ++i) mx = fmaxf(mx, va[i]);
    float s = 0.f;
#pragma unroll
    for (int i = 0; i < NTAGS; ++i) s += __expf(va[i] - mx);
    float na = mx + __logf(s) + emb_[t * 16 + jj];
    alpha = (lane < NTAGS) ? na : -1e30f;
  }
  float v = (lane < NTAGS) ? alpha + endv[lane] : -1e30f;
  float mx = v;
#pragma unroll
  for (int s2 = 32; s2; s2 >>= 1) mx = fmaxf(mx, __shfl_xor(mx, s2));
  float se = __expf(v - mx);
#pragma unroll
  for (int s2 = 32; s2; s2 >>= 1) se += __shfl_xor(se, s2);
  float denom = mx + __logf(se);
  if (lane == 0) {
    float num = numacc + start[tg[0]] + endv[tg[SEQ - 1]];
    nll[b] = denom - num;
  }
}

__global__ void reduce_kernel(const float* __restrict__ nll, float* __restrict__ out) {
  int lane = threadIdx.x;  // 64
  float v = nll[lane] + nll[lane + 64];
#pragma unroll
  for (int s = 32; s; s >>= 1) v += __shfl_xor(v, s);
  if (lane == 0) out[0] = v * (1.f / 128.f);
}

// ---------------- launch ----------------
extern "C" void kernel_launch(void* const* d_in, const int* in_sizes, int n_in,
                              void* d_out, int out_size, void* d_ws, size_t ws_size,
                              hipStream_t stream)
{
  const int*   x        = (const int*)d_in[0];
  const int*   tags     = (const int*)d_in[1];
  const float* emb      = (const float*)d_in[2];
  const float* wih_l0f  = (const float*)d_in[3];
  const float* whh_l0f  = (const float*)d_in[4];
  const float* b_l0f    = (const float*)d_in[5];
  const float* wih_l0b  = (const float*)d_in[6];
  const float* whh_l0b  = (const float*)d_in[7];
  const float* b_l0b    = (const float*)d_in[8];
  const float* wih_l1f  = (const float*)d_in[9];
  const float* whh_l1f  = (const float*)d_in[10];
  const float* b_l1f    = (const float*)d_in[11];
  const float* wih_l1b  = (const float*)d_in[12];
  const float* whh_l1b  = (const float*)d_in[13];
  const float* b_l1b    = (const float*)d_in[14];
  const float* fc_w     = (const float*)d_in[15];
  const float* fc_b     = (const float*)d_in[16];
  const float* crf_start= (const float*)d_in[17];
  const float* crf_end  = (const float*)d_in[18];
  const float* crf_trans= (const float*)d_in[19];

  char* ws = (char*)d_ws;
  f16*   xw16   = (f16*)(ws + OFF_XW);
  f16*   h0     = (f16*)(ws + OFF_H0);
  f16*   e16    = (f16*)(ws + OFF_POOL);   // 40 MB, dead after layer-0 GEMMs
  f16*   h1     = (f16*)(ws + OFF_POOL);   // 64 MB, written during layer-1 rec
  float* em32   = (float*)(ws + OFF_EM);
  f16*   whh16  = (f16*)(ws + OFF_WHH);
  f16*   wih016 = (f16*)(ws + OFF_WIH0);
  f16*   wih116 = (f16*)(ws + OFF_WIH1);
  f16*   fcw16  = (f16*)(ws + OFF_FCW);
  float* fcb32  = (float*)(ws + OFF_FCB);
  f16*   stH    = (f16*)(ws + OFF_STH);
  float* stC    = (float*)(ws + OFF_STC);
  float* nllbuf = (float*)(ws + OFF_NLL);
  const uint32_t* whh32 = (const uint32_t*)whh16;

  // 1) weight packing + embedding gather
  prep_kernel<<<11009, 256, 0, stream>>>(whh_l0f, whh_l0b, whh_l1f, whh_l1b,
                                         wih_l0f, wih_l0b, wih_l1f, wih_l1b,
                                         fc_w, fc_b, whh16, wih016, wih116, fcw16, fcb32);
  embed_kernel<<<(TOKENS * KA0) / 256, 256, 0, stream>>>(x, emb, e16);

  const size_t zstr = (size_t)CTOK * G4H;
  dim3 gch(CTOK / 128, G4H / 128, 2);

  // 2) layer 0: 4 rounds of (chunk GEMM fwd+bwd, 128-step rec)
  for (int r = 0; r < 4; ++r) {
    gemm_kernel<<<gch, 256, 0, stream>>>(e16, KA0, SEQ,
                                         wih016, wih016 + (size_t)G4H * KA0, KA0,
                                         b_l0f, b_l0b, xw16, nullptr, G4H, zstr,
                                         KA0 / 32, G4H, r * CHUNK, (3 - r) * CHUNK);
    rec_kernel<<<256, 1024, 0, stream>>>(xw16, whh32, whh32 + (size_t)G4H * 128,
                                         h0, stH, stC, r);
  }

  // 3) layer 1: same, input = h0
  for (int r = 0; r < 4; ++r) {
    gemm_kernel<<<gch, 256, 0, stream>>>(h0, KA1, SEQ,
                                         wih116, wih116 + (size_t)G4H * KA1, KA1,
                                         b_l1f, b_l1b, xw16, nullptr, G4H, zstr,
                                         KA1 / 32, G4H, r * CHUNK, (3 - r) * CHUNK);
    rec_kernel<<<256, 1024, 0, stream>>>(xw16, whh32 + (size_t)2 * G4H * 128,
                                         whh32 + (size_t)3 * G4H * 128,
                                         h1, stH, stC, r);
  }

  // 4) FC emissions (N padded to 128, store first 16 cols as f32)
  dim3 gfc(TOKENS / 128, 1, 1);
  gemm_kernel<<<gfc, 256, 0, stream>>>(h1, KA1, 128,
                                       fcw16, nullptr, KA1, fcb32, nullptr,
                                       nullptr, em32, 16, 0, KA1 / 32, 16, 0, 0);

  // 5) CRF nll per batch + mean
  crf_kernel<<<BATCH, 64, 0, stream>>>(em32, tags, crf_start, crf_end, crf_trans, nllbuf);
  reduce_kernel<<<1, 64, 0, stream>>>(nllbuf, (float*)d_out);
}

// Round 6
// 2828.480 us; speedup vs baseline: 2.0611x; 2.0611x over previous
//
#include <hip/hip_runtime.h>
#include <cstdint>
#include <cstddef>

// ---------------- problem constants ----------------
#define BATCH   128
#define SEQ     512
#define TOKENS  (BATCH * SEQ)   // 65536
#define EMB_D   300
#define KA0     320             // padded E
#define HID     256
#define G4H     1024            // 4*H
#define KA1     512             // 2*H
#define NTAGS   9
#define CHUNK   128             // seq chunk per round
#define CTOK    (BATCH * CHUNK) // 16384 rows per dir per round

typedef _Float16 f16;
typedef _Float16 f16x2 __attribute__((ext_vector_type(2)));
typedef _Float16 f16x8 __attribute__((ext_vector_type(8)));
typedef float    f32x4 __attribute__((ext_vector_type(4)));

// ---------------- workspace layout (bytes), total ~202 MB ----------------
static constexpr size_t XW_BYTES   = (size_t)2 * CTOK * G4H * 2;    // 67,108,864
static constexpr size_t H_BYTES    = (size_t)TOKENS * KA1 * 2;      // 67,108,864
static constexpr size_t POOL_BYTES = H_BYTES;                       // e16 (40MB) then h1 (64MB)
static constexpr size_t EM_BYTES   = (size_t)TOKENS * 16 * 4;       // 4,194,304
static constexpr size_t WHH_BYTES  = (size_t)4 * G4H * HID * 2;     // 2,097,152
static constexpr size_t WIH0_BYTES = (size_t)2 * G4H * KA0 * 2;     // 1,310,720
static constexpr size_t WIH1_BYTES = (size_t)2 * G4H * KA1 * 2;     // 2,097,152
static constexpr size_t FCW_BYTES  = (size_t)128 * KA1 * 2;         // 131,072
static constexpr size_t FCB_BYTES  = 512;
static constexpr size_t STH_BYTES  = (size_t)2 * BATCH * HID * 2;   // 131,072
static constexpr size_t STC_BYTES  = (size_t)2 * BATCH * HID * 4;   // 262,144
static constexpr size_t NLL_BYTES  = 512;

static constexpr size_t OFF_XW   = 0;
static constexpr size_t OFF_H0   = OFF_XW   + XW_BYTES;
static constexpr size_t OFF_POOL = OFF_H0   + H_BYTES;    // e16 and h1 alias here
static constexpr size_t OFF_EM   = OFF_POOL + POOL_BYTES;
static constexpr size_t OFF_WHH  = OFF_EM   + EM_BYTES;
static constexpr size_t OFF_WIH0 = OFF_WHH  + WHH_BYTES;
static constexpr size_t OFF_WIH1 = OFF_WIH0 + WIH0_BYTES;
static constexpr size_t OFF_FCW  = OFF_WIH1 + WIH1_BYTES;
static constexpr size_t OFF_FCB  = OFF_FCW  + FCW_BYTES;
static constexpr size_t OFF_STH  = OFF_FCB  + FCB_BYTES;
static constexpr size_t OFF_STC  = OFF_STH  + STH_BYTES;
static constexpr size_t OFF_NLL  = OFF_STC  + STC_BYTES;

// ---------------- helpers ----------------
__device__ inline float fdot2(uint32_t a, uint32_t b, float c) {
#if __has_builtin(__builtin_amdgcn_fdot2)
  return __builtin_amdgcn_fdot2(__builtin_bit_cast(f16x2, a),
                                __builtin_bit_cast(f16x2, b), c, false);
#else
  f16x2 ha = __builtin_bit_cast(f16x2, a), hb = __builtin_bit_cast(f16x2, b);
  return c + (float)ha.x * (float)hb.x + (float)ha.y * (float)hb.y;
#endif
}

// LDS chunk swizzle to spread b128 frag reads across banks (GEMM)
__device__ inline int swz(int r, int q) { return q ^ ((r & 3) ^ ((r >> 2) & 3)); }

// ---------------- prep: fp32 -> fp16 weight packing ----------------
__global__ void prep_kernel(
    const float* whh_l0f, const float* whh_l0b, const float* whh_l1f, const float* whh_l1b,
    const float* wih_l0f, const float* wih_l0b,
    const float* wih_l1f, const float* wih_l1b,
    const float* fc_w, const float* fc_b,
    f16* whh16, f16* wih0_16, f16* wih1_16, f16* fcw16, float* fcb32)
{
  int id = blockIdx.x * 256 + threadIdx.x;
  if (id < 1048576) {               // whh: [4][1024][256]
    int which = id >> 18; int off = id & 262143;
    const float* s = which == 0 ? whh_l0f : which == 1 ? whh_l0b
                   : which == 2 ? whh_l1f : whh_l1b;
    whh16[id] = (f16)s[off];
    return;
  }
  id -= 1048576;
  if (id < 655360) {                // wih l0 padded: [2][1024][320]
    int dir = id / 327680; int rem = id - dir * 327680;
    int r = rem / KA0; int k = rem - r * KA0;
    const float* s = dir ? wih_l0b : wih_l0f;
    wih0_16[id] = (f16)(k < EMB_D ? s[r * EMB_D + k] : 0.f);
    return;
  }
  id -= 655360;
  if (id < 1048576) {               // wih l1: [2][1024][512]
    const float* s = (id < 524288) ? wih_l1f : wih_l1b;
    wih1_16[id] = (f16)s[id & 524287];
    return;
  }
  id -= 1048576;
  if (id < 65536) {                 // fcw: [128][512], rows >= 9 zero
    int r = id >> 9;
    fcw16[id] = (f16)(r < NTAGS ? fc_w[id] : 0.f);
    return;
  }
  id -= 65536;
  if (id < 128) fcb32[id] = id < NTAGS ? fc_b[id] : 0.f;
}

// ---------------- embedding gather -> f16 padded ----------------
__global__ void embed_kernel(const int* __restrict__ x, const float* __restrict__ emb,
                             f16* __restrict__ e16)
{
  int id = blockIdx.x * 256 + threadIdx.x;   // over TOKENS*KA0
  if (id >= TOKENS * KA0) return;
  int row = id / KA0, k = id - row * KA0;
  float v = 0.f;
  if (k < EMB_D) v = emb[(size_t)x[row] * EMB_D + k];
  e16[id] = (f16)v;
}

// ---------------- MFMA f16 GEMM: C[M][N] = A[rowmap(M)][K] * B[N][K]^T + bias ----
// 128x128 tile, BK=32, 256 threads (4 waves, 2x2 of 64x64).
__global__ __launch_bounds__(256, 3) void gemm_kernel(
    const f16* __restrict__ A, int lda, int aGrpStride,
    const f16* __restrict__ B0, const f16* __restrict__ B1, int ldb,
    const float* __restrict__ bias0, const float* __restrict__ bias1,
    f16* outH, float* outF, int ldc, size_t outZStride,
    int kChunks, int nLimit, int cbF, int cbB)
{
  __shared__ __align__(16) f16 As[128 * 32];
  __shared__ __align__(16) f16 Bs[128 * 32];
  const int z = blockIdx.z;
  const f16* B = z ? B1 : B0;
  const float* bias = z ? bias1 : bias0;
  const int cb = z ? cbB : cbF;
  const int m0 = blockIdx.x * 128, n0 = blockIdx.y * 128;
  const int aBase = (m0 >> 7) * aGrpStride + cb;
  const int tid = threadIdx.x;
  const int w = tid >> 6, lane = tid & 63;
  const int mw = (w & 1) * 64, nw = (w >> 1) * 64;
  const int fr = lane & 15, fq = lane >> 4;

  f32x4 acc[4][4];
#pragma unroll
  for (int i = 0; i < 4; ++i)
#pragma unroll
    for (int j = 0; j < 4; ++j) acc[i][j] = (f32x4)(0.f);

  const int c0 = tid, c1 = tid + 256;
  const int r0 = c0 >> 2, q0 = c0 & 3, r1c = c1 >> 2, q1 = c1 & 3;

  for (int kc = 0; kc < kChunks; ++kc) {
    const int k0 = kc * 32;
    uint4 a0v = *(const uint4*)(A + (size_t)(aBase + r0)  * lda + k0 + q0 * 8);
    uint4 a1v = *(const uint4*)(A + (size_t)(aBase + r1c) * lda + k0 + q1 * 8);
    uint4 b0v = *(const uint4*)(B + (size_t)(n0 + r0)  * ldb + k0 + q0 * 8);
    uint4 b1v = *(const uint4*)(B + (size_t)(n0 + r1c) * ldb + k0 + q1 * 8);
    __syncthreads();
    *(uint4*)(As + r0  * 32 + swz(r0,  q0) * 8) = a0v;
    *(uint4*)(As + r1c * 32 + swz(r1c, q1) * 8) = a1v;
    *(uint4*)(Bs + r0  * 32 + swz(r0,  q0) * 8) = b0v;
    *(uint4*)(Bs + r1c * 32 + swz(r1c, q1) * 8) = b1v;
    __syncthreads();
    f16x8 af[4], bf[4];
#pragma unroll
    for (int i = 0; i < 4; ++i) {
      int rr = mw + i * 16 + fr;
      af[i] = *(const f16x8*)(As + rr * 32 + swz(rr, fq) * 8);
    }
#pragma unroll
    for (int j = 0; j < 4; ++j) {
      int rr = nw + j * 16 + fr;
      bf[j] = *(const f16x8*)(Bs + rr * 32 + swz(rr, fq) * 8);
    }
#pragma unroll
    for (int i = 0; i < 4; ++i)
#pragma unroll
      for (int j = 0; j < 4; ++j)
        acc[i][j] = __builtin_amdgcn_mfma_f32_16x16x32_f16(af[i], bf[j], acc[i][j], 0, 0, 0);
  }
  // epilogue: C row = (lane>>4)*4 + r, col = lane&15
  f16* oH = outH ? outH + (size_t)z * outZStride : nullptr;
  float* oF = outF;
#pragma unroll
  for (int j = 0; j < 4; ++j) {
    int n = n0 + nw + j * 16 + fr;
    if (n >= nLimit) continue;
    float bs = bias ? bias[n] : 0.f;
#pragma unroll
    for (int i = 0; i < 4; ++i) {
#pragma unroll
      for (int r = 0; r < 4; ++r) {
        int m = m0 + mw + i * 16 + fq * 4 + r;
        float v = acc[i][j][r] + bs;
        if (oH) oH[(size_t)m * ldc + n] = (f16)v;
        else    oF[(size_t)m * ldc + n] = v;
      }
    }
  }
}

// ---------------- persistent LSTM recurrence, 128-step chunk ----------------
// grid 256 = (dir, batch); 1024 threads. Thread (n = tau&255, ks = tau>>8)
// computes partial dots of gates {i,f,g,o} for h-col n over K-seg
// [ks*64, ks*64+64).
// Weight split per thread: 24 uint4 (96 dwords) in VGPRs + 8 uint4 in LDS.
// This is the ONLY feasible balance point: full-reg needs 128 dwords/thread
// (= entire 128-reg unified budget at 16 waves/CU -> r5's scratch-spill
// disaster, 354 MB FETCH/dispatch), while LDS can hold at most 8 uint4/thread
// (131 KB weights + 16 KB part + 1 KB h = 148.5 KB < 160 KB).
// h broadcast reads are shared across all 4 gates; xW terms live only on
// ks==0 (activation) threads and are added once in the reduction.
__global__ __launch_bounds__(1024) void rec_kernel(
    const f16* __restrict__ xw,            // [2][128][CHUNK][1024] f16
    const uint32_t* __restrict__ whh_f, const uint32_t* __restrict__ whh_b,
    f16* __restrict__ hout,
    f16* __restrict__ stateH, float* __restrict__ stateC, int r)
{
  __shared__ __align__(16) uint4 wlds[8 * 1024];  // 131,072 B weight cols [48,64) of each seg
  __shared__ __align__(16) f32x4 part[1024];      // 16 KB partials [ks*256+n]
  __shared__ __align__(16) uint4 hb[2][32];       // h double buffer (256 f16 each)
  const int tau = threadIdx.x;
  const int n   = tau & 255;
  const int ks  = tau >> 8;
  const int bid = blockIdx.x;
  const int dir = bid >> 7;
  const int b   = bid & 127;
  const int chunk = dir ? (3 - r) : r;
  const int tBase = chunk * CHUNK;
  const uint32_t* whh = dir ? whh_b : whh_f;
  const f16* xwp = xw + (size_t)(dir * 128 + b) * CHUNK * 1024;

  // weight preload: gate rows g*256+n, uint4 cols [ks*8, ks*8+8):
  // first 6 -> VGPRs, last 2 -> LDS
  uint4 wv[4][6];
  {
    const uint4* whhq = (const uint4*)whh;
#pragma unroll
    for (int g = 0; g < 4; ++g) {
      const uint4* p = whhq + (size_t)(g * 256 + n) * 32 + ks * 8;
#pragma unroll
      for (int i = 0; i < 6; ++i) wv[g][i] = p[i];
#pragma unroll
      for (int j = 0; j < 2; ++j) wlds[(g * 2 + j) * 1024 + tau] = p[6 + j];
    }
  }
  float cst = 0.f;
  if (tau < 256) {
    f16 hi = (f16)0.f;
    if (r) { hi = stateH[(dir * 128 + b) * 256 + tau]; cst = stateC[(dir * 128 + b) * 256 + tau]; }
    ((f16*)hb[0])[tau] = hi;
  }
  __syncthreads();

  // xW values: only the activation threads (ks==0) carry them
  f16 xc0 = (f16)0.f, xc1 = (f16)0.f, xc2 = (f16)0.f, xc3 = (f16)0.f;
  if (ks == 0) {
    int lr0 = dir ? (CHUNK - 1) : 0;
    const f16* q = xwp + lr0 * 1024;
    xc0 = q[n]; xc1 = q[256 + n]; xc2 = q[512 + n]; xc3 = q[768 + n];
  }

  for (int s = 0; s < CHUNK; ++s) {
    const int lrow = dir ? (CHUNK - 1 - s) : s;
    const size_t token = (size_t)b * 512 + tBase + lrow;
    const int cur = s & 1, nxt = cur ^ 1;
    // prefetch next step's xW (ks==0 only; wave-uniform branch)
    f16 xn0 = (f16)0.f, xn1 = (f16)0.f, xn2 = (f16)0.f, xn3 = (f16)0.f;
    if (ks == 0 && s < CHUNK - 1) {
      int lrn = dir ? (CHUNK - 2 - s) : (s + 1);
      const f16* q = xwp + lrn * 1024;
      xn0 = q[n]; xn1 = q[256 + n]; xn2 = q[512 + n]; xn3 = q[768 + n];
    }
    const uint4* hp = hb[cur] + ks * 8;   // this thread's h segment (8 uint4)
    float a0 = 0.f, a1 = 0.f, a2 = 0.f, a3 = 0.f;
    // register-weight section: h uint4 read once (broadcast), used by 4 gates
#pragma unroll
    for (int i = 0; i < 6; ++i) {
      uint4 h4 = hp[i];
      a0 = fdot2(wv[0][i].x, h4.x, a0); a0 = fdot2(wv[0][i].y, h4.y, a0);
      a0 = fdot2(wv[0][i].z, h4.z, a0); a0 = fdot2(wv[0][i].w, h4.w, a0);
      a1 = fdot2(wv[1][i].x, h4.x, a1); a1 = fdot2(wv[1][i].y, h4.y, a1);
      a1 = fdot2(wv[1][i].z, h4.z, a1); a1 = fdot2(wv[1][i].w, h4.w, a1);
      a2 = fdot2(wv[2][i].x, h4.x, a2); a2 = fdot2(wv[2][i].y, h4.y, a2);
      a2 = fdot2(wv[2][i].z, h4.z, a2); a2 = fdot2(wv[2][i].w, h4.w, a2);
      a3 = fdot2(wv[3][i].x, h4.x, a3); a3 = fdot2(wv[3][i].y, h4.y, a3);
      a3 = fdot2(wv[3][i].z, h4.z, a3); a3 = fdot2(wv[3][i].w, h4.w, a3);
    }
    // LDS-weight section: cols [48,64) of the seg, 2 uint4 per gate
#pragma unroll
    for (int j = 0; j < 2; ++j) {
      uint4 h4 = hp[6 + j];
      {
        uint4 w0 = wlds[(0 + j) * 1024 + tau];
        uint4 w1 = wlds[(2 + j) * 1024 + tau];
        a0 = fdot2(w0.x, h4.x, a0); a0 = fdot2(w0.y, h4.y, a0);
        a0 = fdot2(w0.z, h4.z, a0); a0 = fdot2(w0.w, h4.w, a0);
        a1 = fdot2(w1.x, h4.x, a1); a1 = fdot2(w1.y, h4.y, a1);
        a1 = fdot2(w1.z, h4.z, a1); a1 = fdot2(w1.w, h4.w, a1);
      }
      {
        uint4 w2 = wlds[(4 + j) * 1024 + tau];
        uint4 w3 = wlds[(6 + j) * 1024 + tau];
        a2 = fdot2(w2.x, h4.x, a2); a2 = fdot2(w2.y, h4.y, a2);
        a2 = fdot2(w2.z, h4.z, a2); a2 = fdot2(w2.w, h4.w, a2);
        a3 = fdot2(w3.x, h4.x, a3); a3 = fdot2(w3.y, h4.y, a3);
        a3 = fdot2(w3.z, h4.z, a3); a3 = fdot2(w3.w, h4.w, a3);
      }
    }
    f32x4 pk; pk[0] = a0; pk[1] = a1; pk[2] = a2; pk[3] = a3;
    part[tau] = pk;                       // lane-contiguous, conflict-free
    __syncthreads();
    if (tau < 256) {
      f32x4 p0 = part[n], p1 = part[256 + n], p2 = part[512 + n], p3 = part[768 + n];
      float gi = p0[0] + p1[0] + p2[0] + p3[0] + (float)xc0;
      float gf = p0[1] + p1[1] + p2[1] + p3[1] + (float)xc1;
      float gg = p0[2] + p1[2] + p2[2] + p3[2] + (float)xc2;
      float go = p0[3] + p1[3] + p2[3] + p3[3] + (float)xc3;
      float si = 1.f / (1.f + __expf(-gi));
      float sf = 1.f / (1.f + __expf(-gf));
      float so = 1.f / (1.f + __expf(-go));
      float e2 = __expf(2.f * gg); float tg = 1.f - 2.f / (e2 + 1.f);
      cst = sf * cst + si * tg;
      e2 = __expf(2.f * cst); float tc = 1.f - 2.f / (e2 + 1.f);
      float h = so * tc;
      f16 hh = (f16)h;
      ((f16*)hb[nxt])[tau] = hh;
      hout[token * 512 + dir * 256 + tau] = hh;
    }
    __syncthreads();
    xc0 = xn0; xc1 = xn1; xc2 = xn2; xc3 = xn3;
  }
  // CHUNK even -> final h in hb[0]
  if (tau < 256) {
    stateH[(dir * 128 + b) * 256 + tau] = ((f16*)hb[0])[tau];
    stateC[(dir * 128 + b) * 256 + tau] = cst;
  }
}

// ---------------- CRF: one wave per batch element ----------------
__global__ void crf_kernel(const float* __restrict__ em, const int* __restrict__ tags,
                           const float* __restrict__ start, const float* __restrict__ endv,
                           const float* __restrict__ trans, float* __restrict__ nll)
{
  const int b = blockIdx.x;
  const int lane = threadIdx.x;  // 64
  const float* emb_ = em + (size_t)b * SEQ * 16;
  const int* tg = tags + b * SEQ;

  // numerator, parallel over t
  float numacc = 0.f;
  for (int t = lane; t < SEQ; t += 64) {
    int ct = tg[t];
    numacc += emb_[t * 16 + ct];
    if (t > 0) numacc += trans[tg[t - 1] * NTAGS + ct];
  }
#pragma unroll
  for (int s = 32; s; s >>= 1) numacc += __shfl_xor(numacc, s);

  // forward algorithm: lanes 0..8 hold alpha_j
  int jj = lane < NTAGS ? lane : 0;
  float tr[NTAGS];
#pragma unroll
  for (int i = 0; i < NTAGS; ++i) tr[i] = trans[i * NTAGS + jj];
  float alpha = (lane < NTAGS) ? (start[lane] + emb_[lane]) : -1e30f;
  for (int t = 1; t < SEQ; ++t) {
    float va[NTAGS];
#pragma unroll
    for (int i = 0; i < NTAGS; ++i) va[i] = __shfl(alpha, i) + tr[i];
    float mx = va[0];
#pragma unroll
    for (int i = 1; i < NTAGS; ++i) mx = fmaxf(mx, va[i]);
    float s = 0.f;
#pragma unroll
    for (int i = 0; i < NTAGS; ++i) s += __expf(va[i] - mx);
    float na = mx + __logf(s) + emb_[t * 16 + jj];
    alpha = (lane < NTAGS) ? na : -1e30f;
  }
  float v = (lane < NTAGS) ? alpha + endv[lane] : -1e30f;
  float mx = v;
#pragma unroll
  for (int s2 = 32; s2; s2 >>= 1) mx = fmaxf(mx, __shfl_xor(mx, s2));
  float se = __expf(v - mx);
#pragma unroll
  for (int s2 = 32; s2; s2 >>= 1) se += __shfl_xor(se, s2);
  float denom = mx + __logf(se);
  if (lane == 0) {
    float num = numacc + start[tg[0]] + endv[tg[SEQ - 1]];
    nll[b] = denom - num;
  }
}

__global__ void reduce_kernel(const float* __restrict__ nll, float* __restrict__ out) {
  int lane = threadIdx.x;  // 64
  float v = nll[lane] + nll[lane + 64];
#pragma unroll
  for (int s = 32; s; s >>= 1) v += __shfl_xor(v, s);
  if (lane == 0) out[0] = v * (1.f / 128.f);
}

// ---------------- launch ----------------
extern "C" void kernel_launch(void* const* d_in, const int* in_sizes, int n_in,
                              void* d_out, int out_size, void* d_ws, size_t ws_size,
                              hipStream_t stream)
{
  const int*   x        = (const int*)d_in[0];
  const int*   tags     = (const int*)d_in[1];
  const float* emb      = (const float*)d_in[2];
  const float* wih_l0f  = (const float*)d_in[3];
  const float* whh_l0f  = (const float*)d_in[4];
  const float* b_l0f    = (const float*)d_in[5];
  const float* wih_l0b  = (const float*)d_in[6];
  const float* whh_l0b  = (const float*)d_in[7];
  const float* b_l0b    = (const float*)d_in[8];
  const float* wih_l1f  = (const float*)d_in[9];
  const float* whh_l1f  = (const float*)d_in[10];
  const float* b_l1f    = (const float*)d_in[11];
  const float* wih_l1b  = (const float*)d_in[12];
  const float* whh_l1b  = (const float*)d_in[13];
  const float* b_l1b    = (const float*)d_in[14];
  const float* fc_w     = (const float*)d_in[15];
  const float* fc_b     = (const float*)d_in[16];
  const float* crf_start= (const float*)d_in[17];
  const float* crf_end  = (const float*)d_in[18];
  const float* crf_trans= (const float*)d_in[19];

  char* ws = (char*)d_ws;
  f16*   xw16   = (f16*)(ws + OFF_XW);
  f16*   h0     = (f16*)(ws + OFF_H0);
  f16*   e16    = (f16*)(ws + OFF_POOL);   // 40 MB, dead after layer-0 GEMMs
  f16*   h1     = (f16*)(ws + OFF_POOL);   // 64 MB, written during layer-1 rec
  float* em32   = (float*)(ws + OFF_EM);
  f16*   whh16  = (f16*)(ws + OFF_WHH);
  f16*   wih016 = (f16*)(ws + OFF_WIH0);
  f16*   wih116 = (f16*)(ws + OFF_WIH1);
  f16*   fcw16  = (f16*)(ws + OFF_FCW);
  float* fcb32  = (float*)(ws + OFF_FCB);
  f16*   stH    = (f16*)(ws + OFF_STH);
  float* stC    = (float*)(ws + OFF_STC);
  float* nllbuf = (float*)(ws + OFF_NLL);
  const uint32_t* whh32 = (const uint32_t*)whh16;

  // 1) weight packing + embedding gather
  prep_kernel<<<11009, 256, 0, stream>>>(whh_l0f, whh_l0b, whh_l1f, whh_l1b,
                                         wih_l0f, wih_l0b, wih_l1f, wih_l1b,
                                         fc_w, fc_b, whh16, wih016, wih116, fcw16, fcb32);
  embed_kernel<<<(TOKENS * KA0) / 256, 256, 0, stream>>>(x, emb, e16);

  const size_t zstr = (size_t)CTOK * G4H;
  dim3 gch(CTOK / 128, G4H / 128, 2);

  // 2) layer 0: 4 rounds of (chunk GEMM fwd+bwd, 128-step rec)
  for (int r = 0; r < 4; ++r) {
    gemm_kernel<<<gch, 256, 0, stream>>>(e16, KA0, SEQ,
                                         wih016, wih016 + (size_t)G4H * KA0, KA0,
                                         b_l0f, b_l0b, xw16, nullptr, G4H, zstr,
                                         KA0 / 32, G4H, r * CHUNK, (3 - r) * CHUNK);
    rec_kernel<<<256, 1024, 0, stream>>>(xw16, whh32, whh32 + (size_t)G4H * 128,
                                         h0, stH, stC, r);
  }

  // 3) layer 1: same, input = h0
  for (int r = 0; r < 4; ++r) {
    gemm_kernel<<<gch, 256, 0, stream>>>(h0, KA1, SEQ,
                                         wih116, wih116 + (size_t)G4H * KA1, KA1,
                                         b_l1f, b_l1b, xw16, nullptr, G4H, zstr,
                                         KA1 / 32, G4H, r * CHUNK, (3 - r) * CHUNK);
    rec_kernel<<<256, 1024, 0, stream>>>(xw16, whh32 + (size_t)2 * G4H * 128,
                                         whh32 + (size_t)3 * G4H * 128,
                                         h1, stH, stC, r);
  }

  // 4) FC emissions (N padded to 128, store first 16 cols as f32)
  dim3 gfc(TOKENS / 128, 1, 1);
  gemm_kernel<<<gfc, 256, 0, stream>>>(h1, KA1, 128,
                                       fcw16, nullptr, KA1, fcb32, nullptr,
                                       nullptr, em32, 16, 0, KA1 / 32, 16, 0, 0);

  // 5) CRF nll per batch + mean
  crf_kernel<<<BATCH, 64, 0, stream>>>(em32, tags, crf_start, crf_end, crf_trans, nllbuf);
  reduce_kernel<<<1, 64, 0, stream>>>(nllbuf, (float*)d_out);
}

// Round 7
// 2500.067 us; speedup vs baseline: 2.3319x; 1.1314x over previous
//
#include <hip/hip_runtime.h>
#include <cstdint>
#include <cstddef>

// ---------------- problem constants ----------------
#define BATCH   128
#define SEQ     512
#define TOKENS  (BATCH * SEQ)   // 65536
#define EMB_D   300
#define KA0     320             // padded E
#define HID     256
#define G4H     1024            // 4*H
#define KA1     512             // 2*H
#define NTAGS   9
#define CHUNK   128             // seq chunk per round
#define CTOK    (BATCH * CHUNK) // 16384 rows per dir per round

typedef _Float16 f16;
typedef _Float16 f16x2 __attribute__((ext_vector_type(2)));
typedef _Float16 f16x8 __attribute__((ext_vector_type(8)));
typedef float    f32x4 __attribute__((ext_vector_type(4)));

// ---------------- workspace layout (bytes), total ~202 MB ----------------
static constexpr size_t XW_BYTES   = (size_t)2 * CTOK * G4H * 2;    // 67,108,864
static constexpr size_t H_BYTES    = (size_t)TOKENS * KA1 * 2;      // 67,108,864
static constexpr size_t POOL_BYTES = H_BYTES;                       // e16 (40MB) then h1 (64MB)
static constexpr size_t EM_BYTES   = (size_t)TOKENS * 16 * 4;       // 4,194,304
static constexpr size_t WHH_BYTES  = (size_t)4 * G4H * HID * 2;     // 2,097,152
static constexpr size_t WIH0_BYTES = (size_t)2 * G4H * KA0 * 2;     // 1,310,720
static constexpr size_t WIH1_BYTES = (size_t)2 * G4H * KA1 * 2;     // 2,097,152
static constexpr size_t FCW_BYTES  = (size_t)128 * KA1 * 2;         // 131,072
static constexpr size_t FCB_BYTES  = 512;
static constexpr size_t STH_BYTES  = (size_t)2 * BATCH * HID * 2;   // 131,072
static constexpr size_t STC_BYTES  = (size_t)2 * BATCH * HID * 4;   // 262,144
static constexpr size_t NLL_BYTES  = 512;

static constexpr size_t OFF_XW   = 0;
static constexpr size_t OFF_H0   = OFF_XW   + XW_BYTES;
static constexpr size_t OFF_POOL = OFF_H0   + H_BYTES;    // e16 and h1 alias here
static constexpr size_t OFF_EM   = OFF_POOL + POOL_BYTES;
static constexpr size_t OFF_WHH  = OFF_EM   + EM_BYTES;
static constexpr size_t OFF_WIH0 = OFF_WHH  + WHH_BYTES;
static constexpr size_t OFF_WIH1 = OFF_WIH0 + WIH0_BYTES;
static constexpr size_t OFF_FCW  = OFF_WIH1 + WIH1_BYTES;
static constexpr size_t OFF_FCB  = OFF_FCW  + FCW_BYTES;
static constexpr size_t OFF_STH  = OFF_FCB  + FCB_BYTES;
static constexpr size_t OFF_STC  = OFF_STH  + STH_BYTES;
static constexpr size_t OFF_NLL  = OFF_STC  + STC_BYTES;

// ---------------- helpers ----------------
__device__ inline float fdot2(uint32_t a, uint32_t b, float c) {
#if __has_builtin(__builtin_amdgcn_fdot2)
  return __builtin_amdgcn_fdot2(__builtin_bit_cast(f16x2, a),
                                __builtin_bit_cast(f16x2, b), c, false);
#else
  f16x2 ha = __builtin_bit_cast(f16x2, a), hb = __builtin_bit_cast(f16x2, b);
  return c + (float)ha.x * (float)hb.x + (float)ha.y * (float)hb.y;
#endif
}

// LDS chunk swizzle to spread b128 frag reads across banks (GEMM)
__device__ inline int swz(int r, int q) { return q ^ ((r & 3) ^ ((r >> 2) & 3)); }

// ---------------- prep: fp32 -> fp16 weight packing ----------------
// Whh is repacked for the v7 rec kernel: f16 element (row r = g*256+n,
// col c = ks*128 + i*8 + j) of matrix m lands at
//   whh16[m*262144 + (((g*16+i)*512 + ks*256 + n)*8 + j)]
// so that thread tau = ks*256+n loads uint4 chunk (g,i) at
// wp[(g*16+i)*512 + tau] -- fully coalesced, 52 chunks to arch VGPRs,
// 12 chunks to LDS.
__global__ void prep_kernel(
    const float* whh_l0f, const float* whh_l0b, const float* whh_l1f, const float* whh_l1b,
    const float* wih_l0f, const float* wih_l0b,
    const float* wih_l1f, const float* wih_l1b,
    const float* fc_w, const float* fc_b,
    f16* whh16, f16* wih0_16, f16* wih1_16, f16* fcw16, float* fcb32)
{
  int id = blockIdx.x * 256 + threadIdx.x;
  if (id < 1048576) {               // whh: 4 matrices [1024][256]
    int m = id >> 18; int off = id & 262143;
    const float* s = m == 0 ? whh_l0f : m == 1 ? whh_l0b
                   : m == 2 ? whh_l1f : whh_l1b;
    int r = off >> 8, c = off & 255;
    int g = r >> 8, n = r & 255;
    int ks = c >> 7, i = (c & 127) >> 3, j = c & 7;
    int didx = (((g * 16 + i) * 512) + ks * 256 + n) * 8 + j;
    whh16[m * 262144 + didx] = (f16)s[off];
    return;
  }
  id -= 1048576;
  if (id < 655360) {                // wih l0 padded: [2][1024][320]
    int dir = id / 327680; int rem = id - dir * 327680;
    int r = rem / KA0; int k = rem - r * KA0;
    const float* s = dir ? wih_l0b : wih_l0f;
    wih0_16[id] = (f16)(k < EMB_D ? s[r * EMB_D + k] : 0.f);
    return;
  }
  id -= 655360;
  if (id < 1048576) {               // wih l1: [2][1024][512]
    const float* s = (id < 524288) ? wih_l1f : wih_l1b;
    wih1_16[id] = (f16)s[id & 524287];
    return;
  }
  id -= 1048576;
  if (id < 65536) {                 // fcw: [128][512], rows >= 9 zero
    int r = id >> 9;
    fcw16[id] = (f16)(r < NTAGS ? fc_w[id] : 0.f);
    return;
  }
  id -= 65536;
  if (id < 128) fcb32[id] = id < NTAGS ? fc_b[id] : 0.f;
}

// ---------------- embedding gather -> f16 padded ----------------
__global__ void embed_kernel(const int* __restrict__ x, const float* __restrict__ emb,
                             f16* __restrict__ e16)
{
  int id = blockIdx.x * 256 + threadIdx.x;   // over TOKENS*KA0
  if (id >= TOKENS * KA0) return;
  int row = id / KA0, k = id - row * KA0;
  float v = 0.f;
  if (k < EMB_D) v = emb[(size_t)x[row] * EMB_D + k];
  e16[id] = (f16)v;
}

// ---------------- MFMA f16 GEMM: C[M][N] = A[rowmap(M)][K] * B[N][K]^T + bias ----
// 128x128 tile, BK=32, 256 threads (4 waves, 2x2 of 64x64).
__global__ __launch_bounds__(256, 3) void gemm_kernel(
    const f16* __restrict__ A, int lda, int aGrpStride,
    const f16* __restrict__ B0, const f16* __restrict__ B1, int ldb,
    const float* __restrict__ bias0, const float* __restrict__ bias1,
    f16* outH, float* outF, int ldc, size_t outZStride,
    int kChunks, int nLimit, int cbF, int cbB)
{
  __shared__ __align__(16) f16 As[128 * 32];
  __shared__ __align__(16) f16 Bs[128 * 32];
  const int z = blockIdx.z;
  const f16* B = z ? B1 : B0;
  const float* bias = z ? bias1 : bias0;
  const int cb = z ? cbB : cbF;
  const int m0 = blockIdx.x * 128, n0 = blockIdx.y * 128;
  const int aBase = (m0 >> 7) * aGrpStride + cb;
  const int tid = threadIdx.x;
  const int w = tid >> 6, lane = tid & 63;
  const int mw = (w & 1) * 64, nw = (w >> 1) * 64;
  const int fr = lane & 15, fq = lane >> 4;

  f32x4 acc[4][4];
#pragma unroll
  for (int i = 0; i < 4; ++i)
#pragma unroll
    for (int j = 0; j < 4; ++j) acc[i][j] = (f32x4)(0.f);

  const int c0 = tid, c1 = tid + 256;
  const int r0 = c0 >> 2, q0 = c0 & 3, r1c = c1 >> 2, q1 = c1 & 3;

  for (int kc = 0; kc < kChunks; ++kc) {
    const int k0 = kc * 32;
    uint4 a0v = *(const uint4*)(A + (size_t)(aBase + r0)  * lda + k0 + q0 * 8);
    uint4 a1v = *(const uint4*)(A + (size_t)(aBase + r1c) * lda + k0 + q1 * 8);
    uint4 b0v = *(const uint4*)(B + (size_t)(n0 + r0)  * ldb + k0 + q0 * 8);
    uint4 b1v = *(const uint4*)(B + (size_t)(n0 + r1c) * ldb + k0 + q1 * 8);
    __syncthreads();
    *(uint4*)(As + r0  * 32 + swz(r0,  q0) * 8) = a0v;
    *(uint4*)(As + r1c * 32 + swz(r1c, q1) * 8) = a1v;
    *(uint4*)(Bs + r0  * 32 + swz(r0,  q0) * 8) = b0v;
    *(uint4*)(Bs + r1c * 32 + swz(r1c, q1) * 8) = b1v;
    __syncthreads();
    f16x8 af[4], bf[4];
#pragma unroll
    for (int i = 0; i < 4; ++i) {
      int rr = mw + i * 16 + fr;
      af[i] = *(const f16x8*)(As + rr * 32 + swz(rr, fq) * 8);
    }
#pragma unroll
    for (int j = 0; j < 4; ++j) {
      int rr = nw + j * 16 + fr;
      bf[j] = *(const f16x8*)(Bs + rr * 32 + swz(rr, fq) * 8);
    }
#pragma unroll
    for (int i = 0; i < 4; ++i)
#pragma unroll
      for (int j = 0; j < 4; ++j)
        acc[i][j] = __builtin_amdgcn_mfma_f32_16x16x32_f16(af[i], bf[j], acc[i][j], 0, 0, 0);
  }
  // epilogue: C row = (lane>>4)*4 + r, col = lane&15
  f16* oH = outH ? outH + (size_t)z * outZStride : nullptr;
  float* oF = outF;
#pragma unroll
  for (int j = 0; j < 4; ++j) {
    int n = n0 + nw + j * 16 + fr;
    if (n >= nLimit) continue;
    float bs = bias ? bias[n] : 0.f;
#pragma unroll
    for (int i = 0; i < 4; ++i) {
#pragma unroll
      for (int r = 0; r < 4; ++r) {
        int m = m0 + mw + i * 16 + fq * 4 + r;
        float v = acc[i][j][r] + bs;
        if (oH) oH[(size_t)m * ldc + n] = (f16)v;
        else    oF[(size_t)m * ldc + n] = v;
      }
    }
  }
}

// ---------------- persistent LSTM recurrence v7, 128-step chunk ----------------
// grid 256 = (dir, batch); 512 threads (8 waves/CU -> 256-reg unified budget,
// arch VGPRs up to 256 so fdot2 weight operands avoid AGPR round-trips).
// Thread (n = tau&255, ks = tau>>8) owns ALL 4 gate rows {i,f,g,o} of h-col n
// over its K-half [ks*128, ks*128+128): weights = 64 uint4 = 256 dwords,
// split 52 uint4 -> arch VGPRs + 12 uint4 -> LDS (96 KB).
// Per step: 16 h-broadcast b128 reads shared across 4 gates, 256 fdot2,
// f32x4 partial write, 2-seg reduction + activation on ks==0 threads.
__global__ __launch_bounds__(512) void rec_kernel(
    const f16* __restrict__ xw,            // [2][128][CHUNK][1024] f16
    const uint4* __restrict__ wp_f, const uint4* __restrict__ wp_b,
    f16* __restrict__ hout,
    f16* __restrict__ stateH, float* __restrict__ stateC, int r)
{
  __shared__ __align__(16) uint4 wlds[12 * 512];  // 98,304 B
  __shared__ __align__(16) f32x4 part[512];       // 8 KB
  __shared__ __align__(16) uint4 hb[2][32];       // h double buffer (256 f16 each)
  const int tau = threadIdx.x;
  const int n   = tau & 255;
  const int ks  = tau >> 8;
  const int dir = blockIdx.x >> 7;
  const int b   = blockIdx.x & 127;
  const int chunk = dir ? (3 - r) : r;
  const int tBase = chunk * CHUNK;
  const uint4* wp = dir ? wp_b : wp_f;
  const f16* xwp = xw + (size_t)(dir * 128 + b) * CHUNK * 1024;

  // weight preload: 64 uint4 chunks (g,i); i<13 -> regs, i>=13 -> LDS
  uint4 wv[4][13];
#pragma unroll
  for (int g = 0; g < 4; ++g) {
#pragma unroll
    for (int i = 0; i < 13; ++i) wv[g][i] = wp[(g * 16 + i) * 512 + tau];
#pragma unroll
    for (int i = 13; i < 16; ++i)
      wlds[(g * 3 + (i - 13)) * 512 + tau] = wp[(g * 16 + i) * 512 + tau];
  }
  float cst = 0.f;
  if (tau < 256) {
    f16 hi = (f16)0.f;
    if (r) { hi = stateH[(dir * 128 + b) * 256 + tau]; cst = stateC[(dir * 128 + b) * 256 + tau]; }
    ((f16*)hb[0])[tau] = hi;
  }
  __syncthreads();

  // xW values: only ks==0 (activation) threads carry them
  f16 xc0 = (f16)0.f, xc1 = (f16)0.f, xc2 = (f16)0.f, xc3 = (f16)0.f;
  if (ks == 0) {
    int lr0 = dir ? (CHUNK - 1) : 0;
    const f16* q = xwp + lr0 * 1024;
    xc0 = q[n]; xc1 = q[256 + n]; xc2 = q[512 + n]; xc3 = q[768 + n];
  }

  for (int s = 0; s < CHUNK; ++s) {
    const int lrow = dir ? (CHUNK - 1 - s) : s;
    const size_t token = (size_t)b * 512 + tBase + lrow;
    const int cur = s & 1, nxt = cur ^ 1;
    // prefetch next step's xW (ks==0 only; wave-uniform branch)
    f16 xn0 = (f16)0.f, xn1 = (f16)0.f, xn2 = (f16)0.f, xn3 = (f16)0.f;
    if (ks == 0 && s < CHUNK - 1) {
      int lrn = dir ? (CHUNK - 2 - s) : (s + 1);
      const f16* q = xwp + lrn * 1024;
      xn0 = q[n]; xn1 = q[256 + n]; xn2 = q[512 + n]; xn3 = q[768 + n];
    }
    const uint4* hp = hb[cur] + ks * 16;   // this thread's h half (16 uint4)
    float a0 = 0.f, a1 = 0.f, a2 = 0.f, a3 = 0.f;
    // register-weight chunks (i = 0..12)
#pragma unroll
    for (int i = 0; i < 13; ++i) {
      uint4 h4 = hp[i];
      a0 = fdot2(wv[0][i].x, h4.x, a0); a0 = fdot2(wv[0][i].y, h4.y, a0);
      a0 = fdot2(wv[0][i].z, h4.z, a0); a0 = fdot2(wv[0][i].w, h4.w, a0);
      a1 = fdot2(wv[1][i].x, h4.x, a1); a1 = fdot2(wv[1][i].y, h4.y, a1);
      a1 = fdot2(wv[1][i].z, h4.z, a1); a1 = fdot2(wv[1][i].w, h4.w, a1);
      a2 = fdot2(wv[2][i].x, h4.x, a2); a2 = fdot2(wv[2][i].y, h4.y, a2);
      a2 = fdot2(wv[2][i].z, h4.z, a2); a2 = fdot2(wv[2][i].w, h4.w, a2);
      a3 = fdot2(wv[3][i].x, h4.x, a3); a3 = fdot2(wv[3][i].y, h4.y, a3);
      a3 = fdot2(wv[3][i].z, h4.z, a3); a3 = fdot2(wv[3][i].w, h4.w, a3);
    }
    // LDS-weight chunks (i = 13..15)
#pragma unroll
    for (int i = 13; i < 16; ++i) {
      uint4 h4 = hp[i];
      uint4 w0 = wlds[(0 * 3 + (i - 13)) * 512 + tau];
      uint4 w1 = wlds[(1 * 3 + (i - 13)) * 512 + tau];
      a0 = fdot2(w0.x, h4.x, a0); a0 = fdot2(w0.y, h4.y, a0);
      a0 = fdot2(w0.z, h4.z, a0); a0 = fdot2(w0.w, h4.w, a0);
      a1 = fdot2(w1.x, h4.x, a1); a1 = fdot2(w1.y, h4.y, a1);
      a1 = fdot2(w1.z, h4.z, a1); a1 = fdot2(w1.w, h4.w, a1);
      uint4 w2 = wlds[(2 * 3 + (i - 13)) * 512 + tau];
      uint4 w3 = wlds[(3 * 3 + (i - 13)) * 512 + tau];
      a2 = fdot2(w2.x, h4.x, a2); a2 = fdot2(w2.y, h4.y, a2);
      a2 = fdot2(w2.z, h4.z, a2); a2 = fdot2(w2.w, h4.w, a2);
      a3 = fdot2(w3.x, h4.x, a3); a3 = fdot2(w3.y, h4.y, a3);
      a3 = fdot2(w3.z, h4.z, a3); a3 = fdot2(w3.w, h4.w, a3);
    }
    f32x4 pk; pk[0] = a0; pk[1] = a1; pk[2] = a2; pk[3] = a3;
    part[tau] = pk;                       // lane-contiguous, conflict-free
    __syncthreads();
    if (tau < 256) {
      f32x4 p0 = part[n], p1 = part[256 + n];
      float gi = p0[0] + p1[0] + (float)xc0;
      float gf = p0[1] + p1[1] + (float)xc1;
      float gg = p0[2] + p1[2] + (float)xc2;
      float go = p0[3] + p1[3] + (float)xc3;
      float si = 1.f / (1.f + __expf(-gi));
      float sf = 1.f / (1.f + __expf(-gf));
      float so = 1.f / (1.f + __expf(-go));
      float e2 = __expf(2.f * gg); float tg = 1.f - 2.f / (e2 + 1.f);
      cst = sf * cst + si * tg;
      e2 = __expf(2.f * cst); float tc = 1.f - 2.f / (e2 + 1.f);
      float h = so * tc;
      f16 hh = (f16)h;
      ((f16*)hb[nxt])[tau] = hh;
      hout[token * 512 + dir * 256 + tau] = hh;
    }
    __syncthreads();
    xc0 = xn0; xc1 = xn1; xc2 = xn2; xc3 = xn3;
  }
  // CHUNK even -> final h in hb[0]
  if (tau < 256) {
    stateH[(dir * 128 + b) * 256 + tau] = ((f16*)hb[0])[tau];
    stateC[(dir * 128 + b) * 256 + tau] = cst;
  }
}

// ---------------- CRF: one wave per batch element ----------------
__global__ void crf_kernel(const float* __restrict__ em, const int* __restrict__ tags,
                           const float* __restrict__ start, const float* __restrict__ endv,
                           const float* __restrict__ trans, float* __restrict__ nll)
{
  const int b = blockIdx.x;
  const int lane = threadIdx.x;  // 64
  const float* emb_ = em + (size_t)b * SEQ * 16;
  const int* tg = tags + b * SEQ;

  // numerator, parallel over t
  float numacc = 0.f;
  for (int t = lane; t < SEQ; t += 64) {
    int ct = tg[t];
    numacc += emb_[t * 16 + ct];
    if (t > 0) numacc += trans[tg[t - 1] * NTAGS + ct];
  }
#pragma unroll
  for (int s = 32; s; s >>= 1) numacc += __shfl_xor(numacc, s);

  // forward algorithm: lanes 0..8 hold alpha_j
  int jj = lane < NTAGS ? lane : 0;
  float tr[NTAGS];
#pragma unroll
  for (int i = 0; i < NTAGS; ++i) tr[i] = trans[i * NTAGS + jj];
  float alpha = (lane < NTAGS) ? (start[lane] + emb_[lane]) : -1e30f;
  for (int t = 1; t < SEQ; ++t) {
    float va[NTAGS];
#pragma unroll
    for (int i = 0; i < NTAGS; ++i) va[i] = __shfl(alpha, i) + tr[i];
    float mx = va[0];
#pragma unroll
    for (int i = 1; i < NTAGS; ++i) mx = fmaxf(mx, va[i]);
    float s = 0.f;
#pragma unroll
    for (int i = 0; i < NTAGS; ++i) s += __expf(va[i] - mx);
    float na = mx + __logf(s) + emb_[t * 16 + jj];
    alpha = (lane < NTAGS) ? na : -1e30f;
  }
  float v = (lane < NTAGS) ? alpha + endv[lane] : -1e30f;
  float mx = v;
#pragma unroll
  for (int s2 = 32; s2; s2 >>= 1) mx = fmaxf(mx, __shfl_xor(mx, s2));
  float se = __expf(v - mx);
#pragma unroll
  for (int s2 = 32; s2; s2 >>= 1) se += __shfl_xor(se, s2);
  float denom = mx + __logf(se);
  if (lane == 0) {
    float num = numacc + start[tg[0]] + endv[tg[SEQ - 1]];
    nll[b] = denom - num;
  }
}

__global__ void reduce_kernel(const float* __restrict__ nll, float* __restrict__ out) {
  int lane = threadIdx.x;  // 64
  float v = nll[lane] + nll[lane + 64];
#pragma unroll
  for (int s = 32; s; s >>= 1) v += __shfl_xor(v, s);
  if (lane == 0) out[0] = v * (1.f / 128.f);
}

// ---------------- launch ----------------
extern "C" void kernel_launch(void* const* d_in, const int* in_sizes, int n_in,
                              void* d_out, int out_size, void* d_ws, size_t ws_size,
                              hipStream_t stream)
{
  const int*   x        = (const int*)d_in[0];
  const int*   tags     = (const int*)d_in[1];
  const float* emb      = (const float*)d_in[2];
  const float* wih_l0f  = (const float*)d_in[3];
  const float* whh_l0f  = (const float*)d_in[4];
  const float* b_l0f    = (const float*)d_in[5];
  const float* wih_l0b  = (const float*)d_in[6];
  const float* whh_l0b  = (const float*)d_in[7];
  const float* b_l0b    = (const float*)d_in[8];
  const float* wih_l1f  = (const float*)d_in[9];
  const float* whh_l1f  = (const float*)d_in[10];
  const float* b_l1f    = (const float*)d_in[11];
  const float* wih_l1b  = (const float*)d_in[12];
  const float* whh_l1b  = (const float*)d_in[13];
  const float* b_l1b    = (const float*)d_in[14];
  const float* fc_w     = (const float*)d_in[15];
  const float* fc_b     = (const float*)d_in[16];
  const float* crf_start= (const float*)d_in[17];
  const float* crf_end  = (const float*)d_in[18];
  const float* crf_trans= (const float*)d_in[19];

  char* ws = (char*)d_ws;
  f16*   xw16   = (f16*)(ws + OFF_XW);
  f16*   h0     = (f16*)(ws + OFF_H0);
  f16*   e16    = (f16*)(ws + OFF_POOL);   // 40 MB, dead after layer-0 GEMMs
  f16*   h1     = (f16*)(ws + OFF_POOL);   // 64 MB, written during layer-1 rec
  float* em32   = (float*)(ws + OFF_EM);
  f16*   whh16  = (f16*)(ws + OFF_WHH);
  f16*   wih016 = (f16*)(ws + OFF_WIH0);
  f16*   wih116 = (f16*)(ws + OFF_WIH1);
  f16*   fcw16  = (f16*)(ws + OFF_FCW);
  float* fcb32  = (float*)(ws + OFF_FCB);
  f16*   stH    = (f16*)(ws + OFF_STH);
  float* stC    = (float*)(ws + OFF_STC);
  float* nllbuf = (float*)(ws + OFF_NLL);
  const uint4* wpBase = (const uint4*)whh16;   // packed, 16384 uint4 per matrix

  // 1) weight packing + embedding gather
  prep_kernel<<<11009, 256, 0, stream>>>(whh_l0f, whh_l0b, whh_l1f, whh_l1b,
                                         wih_l0f, wih_l0b, wih_l1f, wih_l1b,
                                         fc_w, fc_b, whh16, wih016, wih116, fcw16, fcb32);
  embed_kernel<<<(TOKENS * KA0) / 256, 256, 0, stream>>>(x, emb, e16);

  const size_t zstr = (size_t)CTOK * G4H;
  dim3 gch(CTOK / 128, G4H / 128, 2);

  // 2) layer 0: 4 rounds of (chunk GEMM fwd+bwd, 128-step rec)
  for (int r = 0; r < 4; ++r) {
    gemm_kernel<<<gch, 256, 0, stream>>>(e16, KA0, SEQ,
                                         wih016, wih016 + (size_t)G4H * KA0, KA0,
                                         b_l0f, b_l0b, xw16, nullptr, G4H, zstr,
                                         KA0 / 32, G4H, r * CHUNK, (3 - r) * CHUNK);
    rec_kernel<<<256, 512, 0, stream>>>(xw16, wpBase, wpBase + 16384,
                                        h0, stH, stC, r);
  }

  // 3) layer 1: same, input = h0
  for (int r = 0; r < 4; ++r) {
    gemm_kernel<<<gch, 256, 0, stream>>>(h0, KA1, SEQ,
                                         wih116, wih116 + (size_t)G4H * KA1, KA1,
                                         b_l1f, b_l1b, xw16, nullptr, G4H, zstr,
                                         KA1 / 32, G4H, r * CHUNK, (3 - r) * CHUNK);
    rec_kernel<<<256, 512, 0, stream>>>(xw16, wpBase + 2 * 16384, wpBase + 3 * 16384,
                                        h1, stH, stC, r);
  }

  // 4) FC emissions (N padded to 128, store first 16 cols as f32)
  dim3 gfc(TOKENS / 128, 1, 1);
  gemm_kernel<<<gfc, 256, 0, stream>>>(h1, KA1, 128,
                                       fcw16, nullptr, KA1, fcb32, nullptr,
                                       nullptr, em32, 16, 0, KA1 / 32, 16, 0, 0);

  // 5) CRF nll per batch + mean
  crf_kernel<<<BATCH, 64, 0, stream>>>(em32, tags, crf_start, crf_end, crf_trans, nllbuf);
  reduce_kernel<<<1, 64, 0, stream>>>(nllbuf, (float*)d_out);
}